// Round 1
// baseline (1220.195 us; speedup 1.0000x reference)
//
#include <hip/hip_runtime.h>
#include <hip/hip_bf16.h>

#define FDIM 9000
#define NBATCH 16384

typedef __attribute__((ext_vector_type(8))) short bf16x8;
typedef __attribute__((ext_vector_type(4))) float f32x4;

__device__ __forceinline__ unsigned short f2b(float f) {
  union { float f; unsigned int u; } v; v.f = f;
  unsigned int u = v.u;
  return (unsigned short)((u + 0x7FFFu + ((u >> 16) & 1u)) >> 16);
}

// ---------------------------------------------------------------------------
// Phase 1: feature-transform GEMM.
// Each block: 64 batch rows x {white, black} = 128 GEMM rows x 128 cols, K=9000.
// fp32 global -> cvt bf16 -> LDS (double buffered), 16x16x32 bf16 MFMA.
// Epilogue: +ft_b, screlu, stm-arrangement, write x (bf16) row-major [B][256].
// ---------------------------------------------------------------------------
__global__ __launch_bounds__(256, 1)
void ft_gemm_kernel(const float* __restrict__ wf, const float* __restrict__ bfeat,
                    const unsigned char* __restrict__ stmb,
                    const float* __restrict__ ftw, const float* __restrict__ ftb,
                    unsigned short* __restrict__ xout)
{
  __shared__ unsigned short ldsA[2][128 * 40];  // pitch 40 bf16 (32 + 8 pad)
  __shared__ unsigned short ldsB[2][128 * 40];
  __shared__ int s_cnt[2];
  __shared__ unsigned char s_xoff[128];

  const int t  = threadIdx.x;
  const int b0 = blockIdx.x * 64;

  // --- stm dtype detection (bool bytes vs int32 vs float32), memory-safe ---
  if (t == 0) { s_cnt[0] = 0; s_cnt[1] = 0; }
  __syncthreads();
  {
    int hi = 0, lo = 0;
    for (int i = t; i < NBATCH; i += 256) {   // scan first 16 KB only (always in-bounds)
      int nz = (stmb[i] != 0);
      if (i & 3) hi += nz; else lo += nz;
    }
    if (hi) atomicAdd(&s_cnt[0], hi);
    if (lo) atomicAdd(&s_cnt[1], lo);
  }
  __syncthreads();
  {
    int h = s_cnt[0], l = s_cnt[1];
    // mode: 0=all-zero, 1=int32 0/1, 2=float32 0.0/1.0, 3=bool bytes
    int mode = (h == 0) ? ((l == 0) ? 0 : 1) : ((l == 0) ? 2 : 3);
    if (t < 128) {
      int b = b0 + (t & 63);
      int v;
      if (mode == 0)      v = 0;
      else if (mode == 1) v = (stmb[4 * b] != 0);
      else if (mode == 2) v = (stmb[4 * b + 3] != 0);
      else                v = (stmb[b] != 0);
      // tile rows 0..63 = white, 64..127 = black
      // x[:,0:128]=stm?black:white  => white col-offset = stm?128:0 ; black opposite
      s_xoff[t] = (unsigned char)((t < 64) ? (v ? 128 : 0) : (v ? 0 : 128));
    }
  }

  // --- staging assignment: 2 threads per row, 16 fp32 each ---
  const int ar = t >> 1;            // 0..127 (GEMM row / weight row)
  const int ac = (t & 1) << 4;      // 0 or 16
  const float* aptr = (ar < 64) ? (wf    + (size_t)(b0 + ar)      * FDIM)
                                : (bfeat + (size_t)(b0 + ar - 64) * FDIM);
  const float* bptr = ftw + (size_t)ar * FDIM;
  const int wr = ar * 40 + ac;      // LDS ushort offset for staging writes

  const int lane = t & 63;
  const int wave = t >> 6;
  const int wm = wave >> 1, wn = wave & 1;
  const int lm = lane & 15, quad = lane >> 4;

  f32x4 acc[4][4];
  #pragma unroll
  for (int i = 0; i < 4; ++i)
    #pragma unroll
    for (int j = 0; j < 4; ++j) acc[i][j] = (f32x4){0.f, 0.f, 0.f, 0.f};

  f32x4 la[4], lb[4];

  auto load_tile = [&](int kt) {
    const int k0 = kt * 32 + ac;
    if (kt < 281) {                 // full tile
      #pragma unroll
      for (int i = 0; i < 4; ++i) {
        la[i] = *(const f32x4*)(aptr + k0 + 4 * i);
        lb[i] = *(const f32x4*)(bptr + k0 + 4 * i);
      }
    } else {                        // tail tile (k 8992..8999 valid, rest zero)
      #pragma unroll
      for (int i = 0; i < 4; ++i) {
        if (k0 + 4 * i + 4 <= FDIM) {
          la[i] = *(const f32x4*)(aptr + k0 + 4 * i);
          lb[i] = *(const f32x4*)(bptr + k0 + 4 * i);
        } else {
          la[i] = (f32x4){0.f, 0.f, 0.f, 0.f};
          lb[i] = (f32x4){0.f, 0.f, 0.f, 0.f};
        }
      }
    }
  };

  auto write_tile = [&](int buf) {
    union { unsigned short us[8]; uint4 v; } pa0, pa1, pb0, pb1;
    #pragma unroll
    for (int i = 0; i < 2; ++i)
      #pragma unroll
      for (int j = 0; j < 4; ++j) {
        pa0.us[i * 4 + j] = f2b(la[i][j]);
        pb0.us[i * 4 + j] = f2b(lb[i][j]);
        pa1.us[i * 4 + j] = f2b(la[2 + i][j]);
        pb1.us[i * 4 + j] = f2b(lb[2 + i][j]);
      }
    *(uint4*)&ldsA[buf][wr]     = pa0.v;
    *(uint4*)&ldsA[buf][wr + 8] = pa1.v;
    *(uint4*)&ldsB[buf][wr]     = pb0.v;
    *(uint4*)&ldsB[buf][wr + 8] = pb1.v;
  };

  // --- pipeline prologue ---
  load_tile(0);
  write_tile(0);
  load_tile(1);                     // tile 1 in flight
  __syncthreads();

  int cur = 0;
  for (int kt = 0; kt < 282; ++kt) {
    bf16x8 af[4], bv[4];
    #pragma unroll
    for (int mi = 0; mi < 4; ++mi)
      af[mi] = *(const bf16x8*)&ldsA[cur][(wm * 64 + mi * 16 + lm) * 40 + quad * 8];
    #pragma unroll
    for (int ni = 0; ni < 4; ++ni)
      bv[ni] = *(const bf16x8*)&ldsB[cur][(wn * 64 + ni * 16 + lm) * 40 + quad * 8];
    #pragma unroll
    for (int mi = 0; mi < 4; ++mi)
      #pragma unroll
      for (int ni = 0; ni < 4; ++ni)
        acc[mi][ni] = __builtin_amdgcn_mfma_f32_16x16x32_bf16(af[mi], bv[ni], acc[mi][ni], 0, 0, 0);
    if (kt < 281) {
      write_tile(cur ^ 1);          // stage tile kt+1 (waits on its global loads)
      if (kt < 280) load_tile(kt + 2);  // issue loads for kt+2 (consumed next iter)
    }
    __syncthreads();
    cur ^= 1;
  }

  // --- epilogue: bias + screlu + stm arrangement, bf16 store ---
  #pragma unroll
  for (int ni = 0; ni < 4; ++ni) {
    const int n = wn * 64 + ni * 16 + lm;
    const float bias = ftb[n];
    #pragma unroll
    for (int mi = 0; mi < 4; ++mi) {
      const f32x4 a = acc[mi][ni];
      #pragma unroll
      for (int r = 0; r < 4; ++r) {
        const int tr = wm * 64 + mi * 16 + quad * 4 + r;  // D row = quad*4+reg
        float v = a[r] + bias;
        v = fminf(fmaxf(v, 0.f), 1.f);
        v = v * v;
        const int b = b0 + (tr & 63);
        const int xcol = n | (int)s_xoff[tr];
        xout[(size_t)b * 256 + xcol] = f2b(v);
      }
    }
  }
}

// ---------------------------------------------------------------------------
// Phase 2: head MLP. 256 blocks x 64 rows. L1 via MFMA (K=256), then scalar
// L2 + output with 4 threads/row and shuffle reduce.
// ---------------------------------------------------------------------------
__global__ __launch_bounds__(256, 1)
void head_kernel(const unsigned short* __restrict__ xws,
                 const float* __restrict__ l1w, const float* __restrict__ l1b,
                 const float* __restrict__ l2w, const float* __restrict__ l2b,
                 const float* __restrict__ outw, const float* __restrict__ outb,
                 float* __restrict__ out)
{
  __shared__ unsigned short Xs[64 * 264];   // 64 rows x 256 bf16, pitch 264
  __shared__ unsigned short W1s[32 * 264];  // 32 x 256 bf16
  __shared__ float A1s[64 * 33];            // l1 activations, pitch 33
  __shared__ float W2s[32 * 33];
  __shared__ float OWs[32];
  __shared__ float L2Bs[32];

  const int t  = threadIdx.x;
  const int r0 = blockIdx.x * 64;

  { // stage X tile (coalesced uint4)
    const uint4* src = (const uint4*)(xws + (size_t)r0 * 256);
    #pragma unroll
    for (int j = 0; j < 8; ++j) {
      int idx = t + j * 256;          // 0..2047, 32 uint4 per row
      int row = idx >> 5;
      int c8  = (idx & 31) * 8;
      *(uint4*)&Xs[row * 264 + c8] = src[idx];
    }
  }
  { // stage W1, cvt fp32->bf16
    #pragma unroll
    for (int j = 0; j < 32; ++j) {
      int i = t + j * 256;            // 0..8191
      int row = i >> 8, col = i & 255;
      W1s[row * 264 + col] = f2b(l1w[i]);
    }
  }
  { // stage W2 (pitch 33), out_w, l2_b
    #pragma unroll
    for (int j = 0; j < 4; ++j) {
      int i = t + j * 256;            // 0..1023
      W2s[(i >> 5) * 33 + (i & 31)] = l2w[i];
    }
    if (t < 32) { OWs[t] = outw[t]; L2Bs[t] = l2b[t]; }
  }
  __syncthreads();

  const int lane = t & 63, wave = t >> 6;
  const int lm = lane & 15, quad = lane >> 4;

  // L1: rows wave*16..+15, all 32 outputs (two n-frags), K=256
  f32x4 c0 = (f32x4){0.f,0.f,0.f,0.f}, c1 = (f32x4){0.f,0.f,0.f,0.f};
  #pragma unroll
  for (int k8 = 0; k8 < 8; ++k8) {
    bf16x8 xa = *(const bf16x8*)&Xs[(wave * 16 + lm) * 264 + k8 * 32 + quad * 8];
    bf16x8 w0 = *(const bf16x8*)&W1s[lm * 264        + k8 * 32 + quad * 8];
    bf16x8 w1 = *(const bf16x8*)&W1s[(16 + lm) * 264 + k8 * 32 + quad * 8];
    c0 = __builtin_amdgcn_mfma_f32_16x16x32_bf16(xa, w0, c0, 0, 0, 0);
    c1 = __builtin_amdgcn_mfma_f32_16x16x32_bf16(xa, w1, c1, 0, 0, 0);
  }
  {
    const float b0v = l1b[lm], b1v = l1b[16 + lm];
    #pragma unroll
    for (int r = 0; r < 4; ++r) {
      int row = wave * 16 + quad * 4 + r;
      float v0 = c0[r] + b0v; v0 = fminf(fmaxf(v0, 0.f), 1.f); A1s[row * 33 + lm]      = v0 * v0;
      float v1 = c1[r] + b1v; v1 = fminf(fmaxf(v1, 0.f), 1.f); A1s[row * 33 + 16 + lm] = v1 * v1;
    }
  }
  __syncthreads();

  // L2 + out: 4 threads per row, 8 l2-outputs each
  const int rl = t >> 2, q = t & 3;
  float partial = 0.f;
  #pragma unroll
  for (int oo = 0; oo < 8; ++oo) {
    int o2 = q * 8 + oo;
    float s = L2Bs[o2];
    #pragma unroll
    for (int o1 = 0; o1 < 32; ++o1)
      s += A1s[rl * 33 + o1] * W2s[o2 * 33 + o1];
    s = fminf(fmaxf(s, 0.f), 1.f);
    partial += s * s * OWs[o2];
  }
  partial += __shfl_xor(partial, 1, 64);
  partial += __shfl_xor(partial, 2, 64);
  if (q == 0) out[r0 + rl] = partial + outb[0];
}

extern "C" void kernel_launch(void* const* d_in, const int* in_sizes, int n_in,
                              void* d_out, int out_size, void* d_ws, size_t ws_size,
                              hipStream_t stream) {
  const float* wf   = (const float*)d_in[0];
  const float* bfe  = (const float*)d_in[1];
  const unsigned char* stm = (const unsigned char*)d_in[2];
  const float* ftw  = (const float*)d_in[3];
  const float* ftb  = (const float*)d_in[4];
  const float* l1w  = (const float*)d_in[5];
  const float* l1b  = (const float*)d_in[6];
  const float* l2w  = (const float*)d_in[7];
  const float* l2b  = (const float*)d_in[8];
  const float* ow   = (const float*)d_in[9];
  const float* ob   = (const float*)d_in[10];

  unsigned short* xws = (unsigned short*)d_ws;  // 16384*256 bf16 = 8 MB
  float* out = (float*)d_out;

  hipLaunchKernelGGL(ft_gemm_kernel, dim3(256), dim3(256), 0, stream,
                     wf, bfe, stm, ftw, ftb, xws);
  hipLaunchKernelGGL(head_kernel, dim3(256), dim3(256), 0, stream,
                     xws, l1w, l1b, l2w, l2b, ow, ob, out);
}